// Round 4
// baseline (343.532 us; speedup 1.0000x reference)
//
#include <hip/hip_runtime.h>
#include <stdint.h>

// Problem: B=1,000,000 rows; IN=64, H=128, OUT=2, 3 heads, per-row routing u in [0,3).
// out[b,:] = Wb[u[b]] @ relu(W1 @ x[b] + b1) + bb[u[b]]
//
// Roofline: mandatory HBM traffic = x(256MB) + u(4MB) + out(8MB) ~ 268MB -> ~43us
// at 6.3 TB/s. Strategy: fully-fused bf16-MFMA kernel, one 16-row tile per wave
// per iteration, W1 staged in LDS (XOR-swizzled), head weights in registers.
//
// R3 lesson: body fits in 64 VGPR -> 8 waves/SIMD possible. Launch 2048 blocks
// (8 blocks/CU, 32 waves/CU = 100% occupancy) and rely on TLP, not in-register
// pipelining (which needs ~96 regs and halves residency).

typedef float f32x4 __attribute__((ext_vector_type(4)));
typedef int   i32x4 __attribute__((ext_vector_type(4)));
typedef short short8 __attribute__((ext_vector_type(8)));
typedef __bf16 bf16x8 __attribute__((ext_vector_type(8)));

static __device__ __forceinline__ f32x4 mfma16(bf16x8 a, bf16x8 b, f32x4 c) {
    return __builtin_amdgcn_mfma_f32_16x16x32_bf16(a, b, c, 0, 0, 0);
}

// Trunk: h^T[128 x 16] = W1[128x64] @ x^T[64x16]  (A = W1 from LDS, B = x from regs)
//   k-packing bijection (per K=32 step s): k = 32s + 8*gamma + j  (gamma = lane>>4)
//   C layout: lane holds h rows n = 16t + 4*gamma + r (r = reg), col = lane&15 = batch row.
// Head: out_all[16 x 6] = relu(h)[16x128] @ Wb_all^T[128x6]
//   A2 row = lane&15 = batch row (same as trunk C -> zero cross-lane movement).
//   k-bijection per step: n = 32s + 16*(j>>2) + 4*gamma + (j&3) = exactly the n-set held.
//   C2: lane holds batch rows base + 4*gamma + r, col = lane&15 = head*2+out combo (<6).
__global__ __launch_bounds__(256, 8) void coil_fused(
    const float* __restrict__ x,
    const int*   __restrict__ u,    // routing ids, int32 on device
    const float* __restrict__ W1,
    const float* __restrict__ b1,
    const float* __restrict__ Wb,   // [3][2][128]
    const float* __restrict__ bb,   // [3][2]
    float* __restrict__ out,        // [B][2]
    int nTiles, int totalWaves)
{
    __shared__ short w1s[128 * 64];   // bf16 bits, XOR-swizzled rows (16 KiB)
    __shared__ float b1s[128];

    const int tid  = threadIdx.x;
    const int lane = tid & 63;
    const int c    = lane & 15;       // "parallel" index within MFMA
    const int g    = lane >> 4;       // k-group gamma

    // ---- stage W1 into LDS as bf16, swizzled: phys = logical ^ ((row&7)<<4) ----
    // 128 rows x 64 bf16 = 1024 chunks of 16 B (8 chunks per row).
    for (int q = tid; q < 1024; q += 256) {
        int row = q >> 3;
        const float* src = W1 + row * 64 + (q & 7) * 8;
        short8 v;
        #pragma unroll
        for (int j = 0; j < 8; ++j) v[j] = __builtin_bit_cast(short, (__bf16)src[j]);
        int phys = (q * 16) ^ ((row & 7) << 4);
        *reinterpret_cast<short8*>(reinterpret_cast<char*>(w1s) + phys) = v;
    }
    if (tid < 128) b1s[tid] = b1[tid];

    // ---- loop-invariant head-weight fragments (Wb) + head bias, per lane ----
    const int ko = c;                  // combo = head*2 + out_pos; valid if < 6
    const bool kvalid = (ko < 6);
    bf16x8 B2[4];
    #pragma unroll
    for (int s = 0; s < 4; ++s) {
        #pragma unroll
        for (int j = 0; j < 8; ++j) {
            int n = 32 * s + ((j >> 2) << 4) + 4 * g + (j & 3);
            B2[s][j] = kvalid ? (__bf16)Wb[ko * 128 + n] : (__bf16)0.0f;
        }
    }
    const float bbr = kvalid ? bb[ko] : 0.0f;

    __syncthreads();

    const int wave = blockIdx.x * (blockDim.x >> 6) + (tid >> 6);
    const char* w1bytes = reinterpret_cast<const char*>(w1s);
    const int sw = (c & 7) << 4;
    const int khead = ko >> 1, opos = ko & 1;

    for (int tile = wave; tile < nTiles; tile += totalWaves) {
        const int base = tile << 4;
        const int m0 = base + 4 * g;

        // x fragments: this lane's batch row = base + c; k = 32s + 8g + j
        const float* xr = x + (size_t)(base + c) * 64 + 8 * g;
        f32x4 xa = *reinterpret_cast<const f32x4*>(xr);       // s=0, j=0..3
        f32x4 xb = *reinterpret_cast<const f32x4*>(xr + 4);   // s=0, j=4..7
        f32x4 xc = *reinterpret_cast<const f32x4*>(xr + 32);  // s=1, j=0..3
        f32x4 xd = *reinterpret_cast<const f32x4*>(xr + 36);  // s=1, j=4..7

        // routing ids for the 4 batch rows this lane will hold after the head MFMA
        i32x4 uv = *reinterpret_cast<const i32x4*>(u + m0);   // 16B-aligned

        bf16x8 B1a, B1b;
        #pragma unroll
        for (int j = 0; j < 4; ++j) {
            B1a[j]     = (__bf16)xa[j];
            B1a[4 + j] = (__bf16)xb[j];
            B1b[j]     = (__bf16)xc[j];
            B1b[4 + j] = (__bf16)xd[j];
        }

        // ---- trunk: 8 h-tiles, bias-seeded accumulators ----
        f32x4 h[8];
        #pragma unroll
        for (int t = 0; t < 8; ++t) {
            f32x4 acc = *reinterpret_cast<const f32x4*>(&b1s[16 * t + 4 * g]); // broadcast
            int lo = (16 * t + c) * 128 + 16 * g;     // logical byte offset, s=0
            short8 A0 = *reinterpret_cast<const short8*>(w1bytes + (lo ^ sw));
            short8 A1 = *reinterpret_cast<const short8*>(w1bytes + ((lo + 64) ^ sw));
            acc = mfma16(__builtin_bit_cast(bf16x8, A0), B1a, acc);
            acc = mfma16(__builtin_bit_cast(bf16x8, A1), B1b, acc);
            h[t] = acc;
        }

        // ---- head: relu + pack + 4 MFMAs over K=128 ----
        f32x4 oacc = {0.f, 0.f, 0.f, 0.f};
        #pragma unroll
        for (int s = 0; s < 4; ++s) {
            bf16x8 A2;
            #pragma unroll
            for (int j = 0; j < 8; ++j) {
                float v = h[2 * s + (j >> 2)][j & 3];
                A2[j] = (__bf16)fmaxf(v, 0.0f);
            }
            oacc = mfma16(A2, B2[s], oacc);
        }

        // ---- select head per row and store (each output element hits exactly 1 lane) ----
        if (khead == uv[0]) out[(m0 + 0) * 2 + opos] = oacc[0] + bbr;
        if (khead == uv[1]) out[(m0 + 1) * 2 + opos] = oacc[1] + bbr;
        if (khead == uv[2]) out[(m0 + 2) * 2 + opos] = oacc[2] + bbr;
        if (khead == uv[3]) out[(m0 + 3) * 2 + opos] = oacc[3] + bbr;
    }
}

extern "C" void kernel_launch(void* const* d_in, const int* in_sizes, int n_in,
                              void* d_out, int out_size, void* d_ws, size_t ws_size,
                              hipStream_t stream) {
    const float* x  = (const float*)d_in[0];
    const int*   u  = (const int*)d_in[1];   // integer inputs are int32 on device
    const float* W1 = (const float*)d_in[2];
    const float* b1 = (const float*)d_in[3];
    const float* Wb = (const float*)d_in[4];
    const float* bb = (const float*)d_in[5];
    float* out = (float*)d_out;

    const int B = in_sizes[1];        // u has one element per row
    const int nTiles = B / 16;        // B = 1,000,000 -> 62,500 (exact)

    // VGPR=64 body -> 8 waves/SIMD -> 8 blocks/CU residency. 256 CU * 8 = 2048
    // blocks, ALL co-resident (100% occupancy), grid-stride ~7.6 tiles/wave.
    int blocks = 2048;
    int totalWaves = blocks * 4;
    if (totalWaves > nTiles) { blocks = (nTiles + 3) / 4; totalWaves = blocks * 4; }

    hipLaunchKernelGGL(coil_fused, dim3(blocks), dim3(256), 0, stream,
                       x, u, W1, b1, Wb, bb, out, nTiles, totalWaves);
}

// Round 5
// 190.178 us; speedup vs baseline: 1.8064x; 1.8064x over previous
//
#include <hip/hip_runtime.h>
#include <stdint.h>

// Problem: B=1,000,000 rows; IN=64, H=128, OUT=2, 3 heads, per-row routing u in [0,3).
// out[b,:] = Wb[u[b]] @ relu(W1 @ x[b] + b1) + bb[u[b]]
//
// Roofline: mandatory HBM = x(256MB) + u(4MB) + out(8MB) ~ 268MB -> ~43us @ 6.3TB/s.
//
// Journal:
//  R2: 99us. VGPR=96, 2048 blocks -> ~5 blocks/CU resident -> 2 sequential rounds.
//  R3: 135us. Forced cap 64 -> partial spill (WRITE 44MB) + half-filled machine.
//  R4: 343us. launch_bounds(256,8) -> VGPR 32 -> 225MB spill writes. Never force-shrink.
//  R5 (this): W1 A-fragments hoisted to 64 loop-invariant VGPRs (in-loop LDS traffic
//  was 16KB/tile = ~29us aggregate LDS-busy -- gone). Trunk/head fused per s-step so
//  only 2 h-tiles live. waves_per_eu(4,4) pins budget at 128 (no spill, no shrink).
//  1024 blocks = 4/CU all-resident, contiguous per-wave chunks (no round quantization).

typedef float f32x4 __attribute__((ext_vector_type(4)));
typedef int   i32x4 __attribute__((ext_vector_type(4)));
typedef __bf16 bf16x8 __attribute__((ext_vector_type(8)));

static __device__ __forceinline__ f32x4 mfma16(bf16x8 a, bf16x8 b, f32x4 c) {
    return __builtin_amdgcn_mfma_f32_16x16x32_bf16(a, b, c, 0, 0, 0);
}

// MFMA k-packing: any bijection (gamma=lane>>4, j)->k works if A and B use the same one.
// Trunk (per K=32 step s): k = 32s + 8*gamma + j; A row (lane&15) -> W1 row 16t+c,
//   B col (lane&15) -> batch row base+c. D: col=lane&15=batch row, row-> h-dim 16t+4g+r.
// Head: A2 row = batch row (matches trunk D -> zero cross-lane movement); k-bijection
//   n = 32s + 16*(j>>2) + 4g + (j&3) = exactly the h-dims this lane holds (t=2s+(j>>2),
//   r=j&3). D2: col=lane&15 = head*2+out combo (<6), row -> batch row base+4g+r.
__global__ __attribute__((amdgpu_flat_work_group_size(256, 256)))
__attribute__((amdgpu_waves_per_eu(4, 4)))
void coil_fused(
    const float* __restrict__ x,
    const int*   __restrict__ u,    // routing ids, int32 on device
    const float* __restrict__ W1,   // [128][64]
    const float* __restrict__ b1,   // [128]
    const float* __restrict__ Wb,   // [3][2][128]
    const float* __restrict__ bb,   // [3][2]
    float* __restrict__ out,        // [B][2]
    int nTiles, int nWaves)
{
    __shared__ float b1s[128];

    const int tid  = threadIdx.x;
    const int lane = tid & 63;
    const int c    = lane & 15;       // MFMA "parallel" index
    const int g    = lane >> 4;       // k-group gamma

    if (tid < 128) b1s[tid] = b1[tid];

    // ---- loop-invariant W1 A-fragments in registers (64 VGPR) ----
    // A0[t]: row 16t+c, k = 8g+j ; A1[t]: row 16t+c, k = 32+8g+j
    bf16x8 A0[8], A1[8];
    {
        const float* wr = W1 + c * 64 + 8 * g;   // + t*16*64 floats per t
        #pragma unroll
        for (int t = 0; t < 8; ++t) {
            f32x4 p0 = *reinterpret_cast<const f32x4*>(wr + t * 1024);
            f32x4 p1 = *reinterpret_cast<const f32x4*>(wr + t * 1024 + 4);
            f32x4 p2 = *reinterpret_cast<const f32x4*>(wr + t * 1024 + 32);
            f32x4 p3 = *reinterpret_cast<const f32x4*>(wr + t * 1024 + 36);
            #pragma unroll
            for (int j = 0; j < 4; ++j) {
                A0[t][j]     = (__bf16)p0[j];
                A0[t][4 + j] = (__bf16)p1[j];
                A1[t][j]     = (__bf16)p2[j];
                A1[t][4 + j] = (__bf16)p3[j];
            }
        }
    }

    // ---- loop-invariant head-weight fragments (16 VGPR) + head bias ----
    const int ko = c;                  // combo = head*2 + out_pos; valid if < 6
    const bool kvalid = (ko < 6);
    bf16x8 B2[4];
    #pragma unroll
    for (int s = 0; s < 4; ++s) {
        #pragma unroll
        for (int j = 0; j < 8; ++j) {
            int n = 32 * s + ((j >> 2) << 4) + 4 * g + (j & 3);
            B2[s][j] = kvalid ? (__bf16)Wb[ko * 128 + n] : (__bf16)0.0f;
        }
    }
    const float bbr = kvalid ? bb[ko] : 0.0f;
    const int khead = ko >> 1, opos = ko & 1;

    __syncthreads();

    // ---- contiguous chunk per wave: no round quantization, sequential DRAM walk ----
    const int w = blockIdx.x * 4 + (tid >> 6);
    const int q = nTiles / nWaves, rm = nTiles % nWaves;
    int tile       = w * q + (w < rm ? w : rm);
    const int tend = tile + q + (w < rm ? 1 : 0);

    for (; tile < tend; ++tile) {
        const int base = tile << 4;
        const int m0 = base + 4 * g;

        // x fragments: lane's batch row = base+c; k = 32s + 8g + j
        const float* xr = x + (size_t)(base + c) * 64 + 8 * g;
        f32x4 xa = *reinterpret_cast<const f32x4*>(xr);       // s=0, j=0..3
        f32x4 xb = *reinterpret_cast<const f32x4*>(xr + 4);   // s=0, j=4..7
        f32x4 xc = *reinterpret_cast<const f32x4*>(xr + 32);  // s=1, j=0..3
        f32x4 xd = *reinterpret_cast<const f32x4*>(xr + 36);  // s=1, j=4..7
        i32x4 uv = *reinterpret_cast<const i32x4*>(u + m0);   // 16B-aligned

        bf16x8 B1a, B1b;
        #pragma unroll
        for (int j = 0; j < 4; ++j) {
            B1a[j]     = (__bf16)xa[j];
            B1a[4 + j] = (__bf16)xb[j];
            B1b[j]     = (__bf16)xc[j];
            B1b[4 + j] = (__bf16)xd[j];
        }

        // ---- fused trunk+head: per head-K-step s, only h[2s],h[2s+1] live ----
        f32x4 oacc = {0.f, 0.f, 0.f, 0.f};
        #pragma unroll
        for (int s = 0; s < 4; ++s) {
            const int t0 = 2 * s, t1 = 2 * s + 1;
            f32x4 h0 = *reinterpret_cast<const f32x4*>(&b1s[16 * t0 + 4 * g]); // bcast
            f32x4 h1 = *reinterpret_cast<const f32x4*>(&b1s[16 * t1 + 4 * g]);
            h0 = mfma16(A0[t0], B1a, h0);
            h1 = mfma16(A0[t1], B1a, h1);
            h0 = mfma16(A1[t0], B1b, h0);
            h1 = mfma16(A1[t1], B1b, h1);
            bf16x8 A2;
            #pragma unroll
            for (int j = 0; j < 4; ++j) {
                A2[j]     = (__bf16)fmaxf(h0[j], 0.0f);
                A2[4 + j] = (__bf16)fmaxf(h1[j], 0.0f);
            }
            oacc = mfma16(A2, B2[s], oacc);
        }

        // ---- per-row head select + store (each out element hits exactly 1 lane) ----
        if (khead == uv[0]) out[(m0 + 0) * 2 + opos] = oacc[0] + bbr;
        if (khead == uv[1]) out[(m0 + 1) * 2 + opos] = oacc[1] + bbr;
        if (khead == uv[2]) out[(m0 + 2) * 2 + opos] = oacc[2] + bbr;
        if (khead == uv[3]) out[(m0 + 3) * 2 + opos] = oacc[3] + bbr;
    }
}

extern "C" void kernel_launch(void* const* d_in, const int* in_sizes, int n_in,
                              void* d_out, int out_size, void* d_ws, size_t ws_size,
                              hipStream_t stream) {
    const float* x  = (const float*)d_in[0];
    const int*   u  = (const int*)d_in[1];   // integer inputs are int32 on device
    const float* W1 = (const float*)d_in[2];
    const float* b1 = (const float*)d_in[3];
    const float* Wb = (const float*)d_in[4];
    const float* bb = (const float*)d_in[5];
    float* out = (float*)d_out;

    const int B = in_sizes[1];        // u has one element per row
    const int nTiles = B / 16;        // 62,500 (exact)

    // waves_per_eu(4,4) -> 4 waves/SIMD -> 4 blocks/CU -> 1024 blocks all co-resident.
    int blocks = 1024;
    int nWaves = blocks * 4;
    if (nWaves > nTiles) { blocks = (nTiles + 3) / 4; nWaves = blocks * 4; }

    hipLaunchKernelGGL(coil_fused, dim3(blocks), dim3(256), 0, stream,
                       x, u, W1, b1, Wb, bb, out, nTiles, nWaves);
}

// Round 6
// 60.893 us; speedup vs baseline: 5.6416x; 3.1232x over previous
//
#include <hip/hip_runtime.h>
#include <stdint.h>

// Problem: B=1,000,000 rows; IN=64, H=128, OUT=2, 3 heads, per-row routing u in [0,3).
// out[b,:] = Wb[u[b]] @ relu(W1 @ x[b] + b1) + bb[u[b]]
//
// Roofline: mandatory HBM = x(256MB) + u(4MB) + out(8MB) ~ 268MB -> ~43us @ 6.3TB/s.
//
// Journal:
//  R2:  99us. LDS-W1, VGPR=96, no spill. Latency-bound: each wave stalls a full HBM
//       RTT per 4KB tile; achieved BW ~1-3 TB/s.
//  R3: 135us. Reg-prefetch + forced 64-VGPR cap -> partial spill + half-empty machine.
//  R4: 343us. launch_bounds(256,8) -> VGPR 32 -> 225MB spill. Never force-shrink regs.
//  R5: 190us. waves_per_eu(4,4) + reg-hoisted W1 -> allocator still picked 64, 71MB
//       spill. Lesson: attributes don't raise the budget; keep live set small instead.
//  R6 (this): latency decoupled via per-wave LDS ring (D=2 tiles) staged with
//       global_load_lds (T3/T4-lite): outstanding loads live in the vmcnt queue, not
//       VGPRs. No barriers (wave-private slots; xrA/xrB separate objects so AA gives
//       counted waits, not drains). x pre-swizzled at the GLOBAL address (m173) so the
//       linear gll write yields a conflict-optimal ds_read_b128 pattern. W1 in LDS
//       (R2-validated). Fused head keeps live h-tiles at 2. No occupancy attributes.

typedef float f32x4 __attribute__((ext_vector_type(4)));
typedef int   i32x4 __attribute__((ext_vector_type(4)));
typedef short short8 __attribute__((ext_vector_type(8)));
typedef __bf16 bf16x8 __attribute__((ext_vector_type(8)));

#define GLOBAL_AS __attribute__((address_space(1)))
#define LDS_AS    __attribute__((address_space(3)))

static __device__ __forceinline__ f32x4 mfma16(bf16x8 a, bf16x8 b, f32x4 c) {
    return __builtin_amdgcn_mfma_f32_16x16x32_bf16(a, b, c, 0, 0, 0);
}

// MFMA k-packing: any bijection (gamma=lane>>4, j)->k works if A and B use the same one.
// Trunk (K=32 step s): k = 32s + 8g + j. D: col=lane&15=batch row, row = h-dim 16t+4g+r.
// Head: A2 row = batch row (matches trunk D -> zero cross-lane movement); k-bijection
//   n = 32s + 16*(j>>2) + 4g + (j&3) = exactly the h-dims this lane holds.
//   D2: col=lane&15 = head*2+out combo (<6), row -> batch row base+4g+r.
__global__ __launch_bounds__(256) void coil_fused(
    const float* __restrict__ x,
    const int*   __restrict__ u,    // routing ids, int32 on device
    const float* __restrict__ W1,   // [128][64]
    const float* __restrict__ b1,   // [128]
    const float* __restrict__ Wb,   // [3][2][128]
    const float* __restrict__ bb,   // [3][2]
    float* __restrict__ out,        // [B][2]
    int nTiles, int nWaves)
{
    __shared__ short w1s[128 * 64];   // 16 KB: W1 as bf16, XOR-swizzled rows
    __shared__ float b1s[128];
    __shared__ float xrA[4][1024];    // 16 KB: per-wave x slot A (4KB each)
    __shared__ float xrB[4][1024];    // 16 KB: per-wave x slot B

    const int tid  = threadIdx.x;
    const int lane = tid & 63;
    const int c    = lane & 15;       // MFMA "parallel" index
    const int g    = lane >> 4;       // k-group gamma
    const int wsl  = tid >> 6;        // wave slot within block

    // ---- stage W1 into LDS as bf16, swizzled: phys = logical ^ ((row&7)<<4) ----
    for (int qq = tid; qq < 1024; qq += 256) {
        int row = qq >> 3;
        const float* src = W1 + row * 64 + (qq & 7) * 8;
        short8 v;
        #pragma unroll
        for (int j = 0; j < 8; ++j) v[j] = __builtin_bit_cast(short, (__bf16)src[j]);
        int phys = (qq * 16) ^ ((row & 7) << 4);
        *reinterpret_cast<short8*>(reinterpret_cast<char*>(w1s) + phys) = v;
    }
    if (tid < 128) b1s[tid] = b1[tid];

    // ---- loop-invariant head-weight fragments (16 VGPR) + head bias ----
    const int ko = c;                  // combo = head*2 + out_pos; valid if < 6
    const bool kvalid = (ko < 6);
    bf16x8 B2[4];
    #pragma unroll
    for (int s = 0; s < 4; ++s) {
        #pragma unroll
        for (int j = 0; j < 8; ++j) {
            int n = 32 * s + ((j >> 2) << 4) + 4 * g + (j & 3);
            B2[s][j] = kvalid ? (__bf16)Wb[ko * 128 + n] : (__bf16)0.0f;
        }
    }
    const float bbr = kvalid ? bb[ko] : 0.0f;
    const int khead = ko >> 1, opos = ko & 1;

    __syncthreads();   // only barrier in the kernel

    // ---- per-lane pre-swizzled GLOBAL offsets for x staging (4 chunks of 1KB) ----
    // LDS phys byte p = i*1024 + lane*16 holds x logical byte p ^ ((row&7)<<4),
    // row = p>>8 (XOR touches bits 4-6 only, row bits unaffected).
    int xoff[4];
    #pragma unroll
    for (int i = 0; i < 4; ++i) {
        int p = i * 1024 + lane * 16;
        xoff[i] = p ^ (((p >> 8) & 7) << 4);
    }

    // ---- x read offsets within a slot (bytes), swizzle-corrected ----
    const int sw  = (c & 7) << 4;
    const int r00 = (c * 256 + g * 32 +   0) ^ sw;   // s=0, j=0..3
    const int r01 = (c * 256 + g * 32 +  16) ^ sw;   // s=0, j=4..7
    const int r10 = (c * 256 + g * 32 + 128) ^ sw;   // s=1, j=0..3
    const int r11 = (c * 256 + g * 32 + 144) ^ sw;   // s=1, j=4..7

    const char* xb8 = reinterpret_cast<const char*>(x);
    const char* w1b = reinterpret_cast<const char*>(w1s);

    auto stage = [&](float* slot, int tile, i32x4& uv) {
        uv = *reinterpret_cast<const i32x4*>(u + tile * 16 + 4 * g);
        const char* src = xb8 + (size_t)tile * 4096;
        LDS_AS char* dst = (LDS_AS char*)slot;
        __builtin_amdgcn_global_load_lds((const GLOBAL_AS void*)(src + xoff[0]), (LDS_AS void*)(dst +    0), 16, 0, 0);
        __builtin_amdgcn_global_load_lds((const GLOBAL_AS void*)(src + xoff[1]), (LDS_AS void*)(dst + 1024), 16, 0, 0);
        __builtin_amdgcn_global_load_lds((const GLOBAL_AS void*)(src + xoff[2]), (LDS_AS void*)(dst + 2048), 16, 0, 0);
        __builtin_amdgcn_global_load_lds((const GLOBAL_AS void*)(src + xoff[3]), (LDS_AS void*)(dst + 3072), 16, 0, 0);
    };

    auto compute = [&](const float* slot, int tile, i32x4 uv) {
        const char* sb = reinterpret_cast<const char*>(slot);
        f32x4 xa = *reinterpret_cast<const f32x4*>(sb + r00);
        f32x4 xv = *reinterpret_cast<const f32x4*>(sb + r01);
        f32x4 xc = *reinterpret_cast<const f32x4*>(sb + r10);
        f32x4 xd = *reinterpret_cast<const f32x4*>(sb + r11);

        bf16x8 B1a, B1b;
        #pragma unroll
        for (int j = 0; j < 4; ++j) {
            B1a[j]     = (__bf16)xa[j];
            B1a[4 + j] = (__bf16)xv[j];
            B1b[j]     = (__bf16)xc[j];
            B1b[4 + j] = (__bf16)xd[j];
        }

        // fused trunk+head: per head-K-step s, only h[2s],h[2s+1] live
        f32x4 oacc = {0.f, 0.f, 0.f, 0.f};
        #pragma unroll
        for (int s = 0; s < 4; ++s) {
            const int t0 = 2 * s, t1 = 2 * s + 1;
            f32x4 h0 = *reinterpret_cast<const f32x4*>(&b1s[16 * t0 + 4 * g]); // bcast
            f32x4 h1 = *reinterpret_cast<const f32x4*>(&b1s[16 * t1 + 4 * g]);
            const int lo0 = (16 * t0 + c) * 128 + 16 * g;
            const int lo1 = (16 * t1 + c) * 128 + 16 * g;
            short8 A00 = *reinterpret_cast<const short8*>(w1b + (lo0 ^ sw));
            short8 A01 = *reinterpret_cast<const short8*>(w1b + ((lo0 + 64) ^ sw));
            short8 A10 = *reinterpret_cast<const short8*>(w1b + (lo1 ^ sw));
            short8 A11 = *reinterpret_cast<const short8*>(w1b + ((lo1 + 64) ^ sw));
            h0 = mfma16(__builtin_bit_cast(bf16x8, A00), B1a, h0);
            h1 = mfma16(__builtin_bit_cast(bf16x8, A10), B1a, h1);
            h0 = mfma16(__builtin_bit_cast(bf16x8, A01), B1b, h0);
            h1 = mfma16(__builtin_bit_cast(bf16x8, A11), B1b, h1);
            bf16x8 A2;
            #pragma unroll
            for (int j = 0; j < 4; ++j) {
                A2[j]     = (__bf16)fmaxf(h0[j], 0.0f);
                A2[4 + j] = (__bf16)fmaxf(h1[j], 0.0f);
            }
            oacc = mfma16(A2, B2[s], oacc);
        }

        const int m0 = tile * 16 + 4 * g;
        if (khead == uv[0]) out[(m0 + 0) * 2 + opos] = oacc[0] + bbr;
        if (khead == uv[1]) out[(m0 + 1) * 2 + opos] = oacc[1] + bbr;
        if (khead == uv[2]) out[(m0 + 2) * 2 + opos] = oacc[2] + bbr;
        if (khead == uv[3]) out[(m0 + 3) * 2 + opos] = oacc[3] + bbr;
    };

    // ---- contiguous PAIR chunks per wave (count always even; no odd tail path) ----
    const int w = blockIdx.x * 4 + wsl;
    const int nPairs = nTiles >> 1;
    const int qv = nPairs / nWaves, rm = nPairs % nWaves;
    int p          = w * qv + (w < rm ? w : rm);
    const int pend = p + qv + (w < rm ? 1 : 0);
    if (p >= pend) return;

    float* slotA = &xrA[wsl][0];
    float* slotB = &xrB[wsl][0];
    const int lastT = nTiles - 1;

    i32x4 uvA, uvB;
    stage(slotA, 2 * p,     uvA);
    stage(slotB, 2 * p + 1, uvB);

    for (; p < pend; ++p) {
        const int tA = 2 * p, tB = 2 * p + 1;
        compute(slotA, tA, uvA);                               // uses uvA by value
        stage(slotA, (tA + 2 <= lastT) ? tA + 2 : lastT, uvA); // refill slot A
        compute(slotB, tB, uvB);
        stage(slotB, (tB + 2 <= lastT) ? tB + 2 : lastT, uvB); // refill slot B
    }
}

extern "C" void kernel_launch(void* const* d_in, const int* in_sizes, int n_in,
                              void* d_out, int out_size, void* d_ws, size_t ws_size,
                              hipStream_t stream) {
    const float* x  = (const float*)d_in[0];
    const int*   u  = (const int*)d_in[1];   // integer inputs are int32 on device
    const float* W1 = (const float*)d_in[2];
    const float* b1 = (const float*)d_in[3];
    const float* Wb = (const float*)d_in[4];
    const float* bb = (const float*)d_in[5];
    float* out = (float*)d_out;

    const int B = in_sizes[1];        // u has one element per row
    const int nTiles = B / 16;        // 62,500 (exact)

    // LDS/block = 48.5KB -> 3 blocks/CU -> 768 blocks all co-resident (12 waves/CU),
    // each wave holding an 8KB 2-tile ring in flight.
    int blocks = 768;
    int nWaves = blocks * 4;
    int nPairs = nTiles / 2;
    if (nWaves > nPairs) { blocks = (nPairs + 3) / 4; nWaves = blocks * 4; }

    hipLaunchKernelGGL(coil_fused, dim3(blocks), dim3(256), 0, stream,
                       x, u, W1, b1, Wb, bb, out, nTiles, nWaves);
}

// Round 7
// 53.171 us; speedup vs baseline: 6.4609x; 1.1452x over previous
//
#include <hip/hip_runtime.h>
#include <stdint.h>

// Problem: B=1,000,000 rows; IN=64, H=128, OUT=2, 3 heads, per-row routing u in [0,3).
// out[b,:] = Wb[u[b]] @ relu(W1 @ x[b] + b1) + bb[u[b]]
//
// Roofline: mandatory HBM = x(256MB) + u(4MB) + out(8MB) ~ 268MB -> ~43us @ 6.3TB/s.
//
// Journal:
//  R2:  99us. LDS-W1, VGPR=96, no spill. Latency-bound (no overlap within wave).
//  R3: 135us. Reg-prefetch + forced 64-VGPR cap -> partial spill + half-empty machine.
//  R4: 343us. launch_bounds(256,8) -> VGPR 32 -> 225MB spill. Never force-shrink regs.
//  R5: 190us. waves_per_eu(4,4) -> still 64 VGPR, 71MB spill. Attributes don't help.
//  R6:  61us. Per-wave LDS ring (2 slots) + global_load_lds: outstanding loads live in
//       the vmcnt queue, not VGPRs. WIN. Remaining: 44 LDS ops/pair (~27us LDS-pipe
//       aggregate, W1 frags read twice per pair) + wait only ~300cyc after issue.
//  R7 (this): pair-shared compute -- one 8KB slot holds 2 tiles; W1/b1 fragments read
//       ONCE per s-step and reused for both tiles (LDS ops/pair 44->32); stage(p+1)
//       issued right after x ds_reads retire (explicit lgkmcnt(0) -> no DMA/read race
//       on the single slot), so the vmcnt wait lands a full compute (~950cyc) after
//       issue -- covers HBM latency even if the compiler drains vmcnt(0).

typedef float f32x4 __attribute__((ext_vector_type(4)));
typedef int   i32x4 __attribute__((ext_vector_type(4)));
typedef short short8 __attribute__((ext_vector_type(8)));
typedef __bf16 bf16x8 __attribute__((ext_vector_type(8)));

#define GLOBAL_AS __attribute__((address_space(1)))
#define LDS_AS    __attribute__((address_space(3)))

static __device__ __forceinline__ f32x4 mfma16(bf16x8 a, bf16x8 b, f32x4 c) {
    return __builtin_amdgcn_mfma_f32_16x16x32_bf16(a, b, c, 0, 0, 0);
}

// MFMA k-packing: any bijection (gamma=lane>>4, j)->k works if A and B use the same one.
// Trunk (K=32 step s): k = 32s + 8g + j. D: col=lane&15=batch row, row = h-dim 16t+4g+r.
// Head: A2 row = batch row (matches trunk D -> zero cross-lane movement); k-bijection
//   n = 32s + 16*(j>>2) + 4g + (j&3) = exactly the h-dims this lane holds.
//   D2: col=lane&15 = head*2+out combo (<6), row -> batch row base+4g+r.
__global__ __launch_bounds__(256) void coil_fused(
    const float* __restrict__ x,
    const int*   __restrict__ u,    // routing ids, int32 on device
    const float* __restrict__ W1,   // [128][64]
    const float* __restrict__ b1,   // [128]
    const float* __restrict__ Wb,   // [3][2][128]
    const float* __restrict__ bb,   // [3][2]
    float* __restrict__ out,        // [B][2]
    int nPairs, int nWaves)
{
    __shared__ short w1s[128 * 64];   // 16 KB: W1 as bf16, XOR-swizzled rows
    __shared__ float b1s[128];
    __shared__ float xsl[4][2048];    // 32 KB: per-wave pair slot (8KB each)

    const int tid  = threadIdx.x;
    const int lane = tid & 63;
    const int c    = lane & 15;       // MFMA "parallel" index
    const int g    = lane >> 4;       // k-group gamma
    const int wsl  = tid >> 6;        // wave slot within block

    // ---- stage W1 into LDS as bf16, swizzled: phys = logical ^ ((row&7)<<4) ----
    for (int qq = tid; qq < 1024; qq += 256) {
        int row = qq >> 3;
        const float* src = W1 + row * 64 + (qq & 7) * 8;
        short8 v;
        #pragma unroll
        for (int j = 0; j < 8; ++j) v[j] = __builtin_bit_cast(short, (__bf16)src[j]);
        int phys = (qq * 16) ^ ((row & 7) << 4);
        *reinterpret_cast<short8*>(reinterpret_cast<char*>(w1s) + phys) = v;
    }
    if (tid < 128) b1s[tid] = b1[tid];

    // ---- loop-invariant head-weight fragments (16 VGPR) + head bias ----
    const int ko = c;                  // combo = head*2 + out_pos; valid if < 6
    const bool kvalid = (ko < 6);
    bf16x8 B2[4];
    #pragma unroll
    for (int s = 0; s < 4; ++s) {
        #pragma unroll
        for (int j = 0; j < 8; ++j) {
            int n = 32 * s + ((j >> 2) << 4) + 4 * g + (j & 3);
            B2[s][j] = kvalid ? (__bf16)Wb[ko * 128 + n] : (__bf16)0.0f;
        }
    }
    const float bbr = kvalid ? bb[ko] : 0.0f;
    const int khead = ko >> 1, opos = ko & 1;

    __syncthreads();   // only barrier in the kernel

    // ---- per-lane pre-swizzled GLOBAL offsets for x staging (8 chunks of 1KB) ----
    // LDS phys byte P = i*1024 + lane*16 holds x logical byte P ^ ((P>>8 & 7)<<4)
    // (XOR touches bits 4-6 only; row bits unaffected).
    int xoff[8];
    #pragma unroll
    for (int i = 0; i < 8; ++i) {
        int p = i * 1024 + lane * 16;
        xoff[i] = p ^ (((p >> 8) & 7) << 4);
    }

    // ---- x read offsets within the slot (bytes), swizzle-corrected; tile B = +4096 ----
    const int sw  = (c & 7) << 4;
    const int r00 = (c * 256 + g * 32 +   0) ^ sw;   // s=0, j=0..3
    const int r01 = (c * 256 + g * 32 +  16) ^ sw;   // s=0, j=4..7
    const int r10 = (c * 256 + g * 32 + 128) ^ sw;   // s=1, j=0..3
    const int r11 = (c * 256 + g * 32 + 144) ^ sw;   // s=1, j=4..7

    const char* xb8 = reinterpret_cast<const char*>(x);
    const char* w1b = reinterpret_cast<const char*>(w1s);
    float* slot = &xsl[wsl][0];
    LDS_AS char* dst = (LDS_AS char*)slot;
    const char* sb = reinterpret_cast<const char*>(slot);

    auto stage = [&](int pairIdx, i32x4& uvA, i32x4& uvB) {
        const int t0 = pairIdx * 2;
        uvA = *reinterpret_cast<const i32x4*>(u + t0 * 16 + 4 * g);
        uvB = *reinterpret_cast<const i32x4*>(u + t0 * 16 + 16 + 4 * g);
        const char* src = xb8 + (size_t)t0 * 4096;
        #pragma unroll
        for (int i = 0; i < 8; ++i)
            __builtin_amdgcn_global_load_lds((const GLOBAL_AS void*)(src + xoff[i]),
                                             (LDS_AS void*)(dst + i * 1024), 16, 0, 0);
    };

    // ---- contiguous pair chunk per wave ----
    const int w = blockIdx.x * 4 + wsl;
    const int qv = nPairs / nWaves, rm = nPairs % nWaves;
    int p          = w * qv + (w < rm ? w : rm);
    const int pend = p + qv + (w < rm ? 1 : 0);
    if (p >= pend) return;

    i32x4 uvA, uvB, nuvA, nuvB;
    stage(p, uvA, uvB);

    for (; p < pend; ++p) {
        // ---- read both tiles' x fragments (waits on this slot's in-flight glls) ----
        f32x4 xaA = *reinterpret_cast<const f32x4*>(sb + r00);
        f32x4 xbA = *reinterpret_cast<const f32x4*>(sb + r01);
        f32x4 xcA = *reinterpret_cast<const f32x4*>(sb + r10);
        f32x4 xdA = *reinterpret_cast<const f32x4*>(sb + r11);
        f32x4 xaB = *reinterpret_cast<const f32x4*>(sb + 4096 + r00);
        f32x4 xbB = *reinterpret_cast<const f32x4*>(sb + 4096 + r01);
        f32x4 xcB = *reinterpret_cast<const f32x4*>(sb + 4096 + r10);
        f32x4 xdB = *reinterpret_cast<const f32x4*>(sb + 4096 + r11);

        // ensure the ds_reads above retired before the DMA below can overwrite the slot
        asm volatile("s_waitcnt lgkmcnt(0)" ::: "memory");

        // ---- refill slot with next pair (clamped restage on the last iteration) ----
        stage((p + 1 < pend) ? p + 1 : p, nuvA, nuvB);

        bf16x8 B1aA, B1bA, B1aB, B1bB;
        #pragma unroll
        for (int j = 0; j < 4; ++j) {
            B1aA[j] = (__bf16)xaA[j];  B1aA[4 + j] = (__bf16)xbA[j];
            B1bA[j] = (__bf16)xcA[j];  B1bA[4 + j] = (__bf16)xdA[j];
            B1aB[j] = (__bf16)xaB[j];  B1aB[4 + j] = (__bf16)xbB[j];
            B1bB[j] = (__bf16)xcB[j];  B1bB[4 + j] = (__bf16)xdB[j];
        }

        // ---- fused trunk+head, W1/b1 fragments shared by both tiles ----
        f32x4 oaccA = {0.f, 0.f, 0.f, 0.f};
        f32x4 oaccB = {0.f, 0.f, 0.f, 0.f};
        #pragma unroll
        for (int s = 0; s < 4; ++s) {
            const int t0 = 2 * s, t1 = 2 * s + 1;
            f32x4 bia0 = *reinterpret_cast<const f32x4*>(&b1s[16 * t0 + 4 * g]); // bcast
            f32x4 bia1 = *reinterpret_cast<const f32x4*>(&b1s[16 * t1 + 4 * g]);
            const int lo0 = (16 * t0 + c) * 128 + 16 * g;
            const int lo1 = (16 * t1 + c) * 128 + 16 * g;
            short8 A00 = *reinterpret_cast<const short8*>(w1b + (lo0 ^ sw));
            short8 A01 = *reinterpret_cast<const short8*>(w1b + ((lo0 + 64) ^ sw));
            short8 A10 = *reinterpret_cast<const short8*>(w1b + (lo1 ^ sw));
            short8 A11 = *reinterpret_cast<const short8*>(w1b + ((lo1 + 64) ^ sw));
            f32x4 h0A = bia0, h1A = bia1, h0B = bia0, h1B = bia1;
            h0A = mfma16(__builtin_bit_cast(bf16x8, A00), B1aA, h0A);
            h0B = mfma16(__builtin_bit_cast(bf16x8, A00), B1aB, h0B);
            h1A = mfma16(__builtin_bit_cast(bf16x8, A10), B1aA, h1A);
            h1B = mfma16(__builtin_bit_cast(bf16x8, A10), B1aB, h1B);
            h0A = mfma16(__builtin_bit_cast(bf16x8, A01), B1bA, h0A);
            h0B = mfma16(__builtin_bit_cast(bf16x8, A01), B1bB, h0B);
            h1A = mfma16(__builtin_bit_cast(bf16x8, A11), B1bA, h1A);
            h1B = mfma16(__builtin_bit_cast(bf16x8, A11), B1bB, h1B);
            bf16x8 A2A, A2B;
            #pragma unroll
            for (int j = 0; j < 4; ++j) {
                A2A[j]     = (__bf16)fmaxf(h0A[j], 0.0f);
                A2A[4 + j] = (__bf16)fmaxf(h1A[j], 0.0f);
                A2B[j]     = (__bf16)fmaxf(h0B[j], 0.0f);
                A2B[4 + j] = (__bf16)fmaxf(h1B[j], 0.0f);
            }
            oaccA = mfma16(A2A, B2[s], oaccA);
            oaccB = mfma16(A2B, B2[s], oaccB);
        }

        // ---- per-row head select + store (each out element hits exactly 1 lane) ----
        const int m0 = p * 32 + 4 * g;          // tile A rows; tile B rows = +16
        if (khead == uvA[0]) out[(m0 +  0) * 2 + opos] = oaccA[0] + bbr;
        if (khead == uvA[1]) out[(m0 +  1) * 2 + opos] = oaccA[1] + bbr;
        if (khead == uvA[2]) out[(m0 +  2) * 2 + opos] = oaccA[2] + bbr;
        if (khead == uvA[3]) out[(m0 +  3) * 2 + opos] = oaccA[3] + bbr;
        if (khead == uvB[0]) out[(m0 + 16) * 2 + opos] = oaccB[0] + bbr;
        if (khead == uvB[1]) out[(m0 + 17) * 2 + opos] = oaccB[1] + bbr;
        if (khead == uvB[2]) out[(m0 + 18) * 2 + opos] = oaccB[2] + bbr;
        if (khead == uvB[3]) out[(m0 + 19) * 2 + opos] = oaccB[3] + bbr;

        uvA = nuvA; uvB = nuvB;
    }
}

extern "C" void kernel_launch(void* const* d_in, const int* in_sizes, int n_in,
                              void* d_out, int out_size, void* d_ws, size_t ws_size,
                              hipStream_t stream) {
    const float* x  = (const float*)d_in[0];
    const int*   u  = (const int*)d_in[1];   // integer inputs are int32 on device
    const float* W1 = (const float*)d_in[2];
    const float* b1 = (const float*)d_in[3];
    const float* Wb = (const float*)d_in[4];
    const float* bb = (const float*)d_in[5];
    float* out = (float*)d_out;

    const int B = in_sizes[1];        // u has one element per row
    const int nTiles = B / 16;        // 62,500 (exact)
    const int nPairs = nTiles / 2;    // 31,250 (exact)

    // LDS/block = 48.5KB -> 3 blocks/CU -> 768 blocks all co-resident (12 waves/CU),
    // each wave cycling one 8KB pair-slot staged one pair ahead.
    int blocks = 768;
    int nWaves = blocks * 4;
    if (nWaves > nPairs) { blocks = (nPairs + 3) / 4; nWaves = blocks * 4; }

    hipLaunchKernelGGL(coil_fused, dim3(blocks), dim3(256), 0, stream,
                       x, u, W1, b1, Wb, bb, out, nPairs, nWaves);
}